// Round 3
// baseline (1147.710 us; speedup 1.0000x reference)
//
#include <hip/hip_runtime.h>
#include <hip/hip_bf16.h>

#define N_NODES 50000
#define N_EDGES 800000
#define F_IN 1024
#define F_MID 256

// Dropout mask variant (JAX threefry counter mapping), counter=(c0,c1):
//  1 = (0,f) -> out x0            [FAILED r1: 0.494]
//  2 = (0,f) -> out x1            [FAILED r2: 0.441]
//  3 = legacy split-halves
//  6 = (0,f) -> x0 ^ x1  (JAX partitionable path, bit_width<=32)  [this round]
#define MASK_VARIANT 6

// ---------------- threefry2x32 (JAX-exact, key = (0,42)) ----------------
__device__ __forceinline__ void tf_round(unsigned &x0, unsigned &x1, int r) {
    x0 += x1;
    x1 = (x1 << r) | (x1 >> (32 - r));
    x1 ^= x0;
}

__device__ __forceinline__ void threefry2x32(unsigned c0, unsigned c1,
                                             unsigned &o0, unsigned &o1) {
    const unsigned ks0 = 0u;    // jax.random.key(42) -> data (0, 42)
    const unsigned ks1 = 42u;
    const unsigned ks2 = ks0 ^ ks1 ^ 0x1BD11BDAu;
    unsigned x0 = c0 + ks0;
    unsigned x1 = c1 + ks1;
    tf_round(x0,x1,13); tf_round(x0,x1,15); tf_round(x0,x1,26); tf_round(x0,x1,6);
    x0 += ks1; x1 += ks2 + 1u;
    tf_round(x0,x1,17); tf_round(x0,x1,29); tf_round(x0,x1,16); tf_round(x0,x1,24);
    x0 += ks2; x1 += ks0 + 2u;
    tf_round(x0,x1,13); tf_round(x0,x1,15); tf_round(x0,x1,26); tf_round(x0,x1,6);
    x0 += ks0; x1 += ks1 + 3u;
    tf_round(x0,x1,17); tf_round(x0,x1,29); tf_round(x0,x1,16); tf_round(x0,x1,24);
    x0 += ks1; x1 += ks2 + 4u;
    tf_round(x0,x1,13); tf_round(x0,x1,15); tf_round(x0,x1,26); tf_round(x0,x1,6);
    x0 += ks2; x1 += ks0 + 5u;
    o0 = x0; o1 = x1;
}

__device__ __forceinline__ int keep_mask(unsigned f) {
    unsigned bits, o0, o1;
#if MASK_VARIANT == 1
    threefry2x32(0u, f, o0, o1); bits = o0;
#elif MASK_VARIANT == 2
    threefry2x32(0u, f, o0, o1); bits = o1;
#elif MASK_VARIANT == 3
    const unsigned HALF = (unsigned)(N_NODES * F_MID / 2); // 6400000
    if (f < HALF) { threefry2x32(f, f + HALF, o0, o1); bits = o0; }
    else          { threefry2x32(f - HALF, f, o0, o1); bits = o1; }
#elif MASK_VARIANT == 6
    threefry2x32(0u, f, o0, o1); bits = o0 ^ o1;
#endif
    return (bits >> 31) == 0u;   // uniform [0,1) < 0.5  <=>  MSB clear
}

// ---------------- graph preprocessing ----------------
// flag semantics: 1 -> edge_index is int64 (read lo words), 0 -> int32
__global__ __launch_bounds__(256) void k_init(int* deg, int* cursor, int* counter,
                                              int* flag) {
    int i = blockIdx.x * 256 + threadIdx.x;
    if (i < N_NODES) { deg[i] = 1; cursor[i] = 0; }   // deg starts at 1 (self-loop)
    if (i == 0) { counter[0] = 0; flag[0] = 1; }
}

__global__ __launch_bounds__(256) void k_detect(const int* __restrict__ ei,
                                                int* __restrict__ flag) {
    // sample odd words across both src and dst halves (int64 hypothesis: all 0)
    int tid = threadIdx.x;
    int nz = 0;
    for (int k = tid; k < 1024; k += 256) {
        nz |= (ei[2 * k + 1] != 0);
        nz |= (ei[2 * N_EDGES + 2 * k + 1] != 0);
    }
    if (nz) atomicAnd(flag, 0);
}

__device__ __forceinline__ int ld_src(const int* ei, int e, int is64) {
    return is64 ? ei[2 * e] : ei[e];
}
__device__ __forceinline__ int ld_dst(const int* ei, int e, int is64) {
    return is64 ? ei[2 * N_EDGES + 2 * e] : ei[N_EDGES + e];
}

__global__ __launch_bounds__(256) void k_count(const int* __restrict__ ei,
                                               int* __restrict__ deg,
                                               const int* __restrict__ flag) {
    int e = blockIdx.x * 256 + threadIdx.x;
    int is64 = flag[0];
    if (e < N_EDGES) atomicAdd(&deg[ld_dst(ei, e, is64)], 1);
}

__global__ __launch_bounds__(256) void k_rows(const int* __restrict__ deg,
                                              float* __restrict__ dinv,
                                              int* __restrict__ rowst,
                                              int* __restrict__ counter) {
    int i = blockIdx.x * 256 + threadIdx.x;
    if (i < N_NODES) {
        dinv[i] = rsqrtf((float)deg[i]);
        rowst[i] = atomicAdd(counter, deg[i] - 1);   // row segments, arbitrary order
    }
}

__global__ __launch_bounds__(256) void k_fill(const int* __restrict__ ei,
                                              const int* __restrict__ rowst,
                                              int* __restrict__ cursor,
                                              int* __restrict__ csr,
                                              const int* __restrict__ flag) {
    int e = blockIdx.x * 256 + threadIdx.x;
    int is64 = flag[0];
    if (e < N_EDGES) {
        int d = ld_dst(ei, e, is64);
        int pos = rowst[d] + atomicAdd(&cursor[d], 1);
        csr[pos] = ld_src(ei, e, is64);
    }
}

// ---------------- f32 tiled GEMM: C[M,N] = A[M,K] @ B[K,N] (+bias) ----------------
// 64x64 tile, BK=16, 256 threads, 4x4 per thread.
__global__ __launch_bounds__(256) void k_gemm(const float* __restrict__ A,
                                              const float* __restrict__ B,
                                              const float* __restrict__ bias,
                                              float* __restrict__ C,
                                              int M, int N, int K, int has_bias) {
    __shared__ __align__(16) float As[16][68];
    __shared__ __align__(16) float Bs[16][64];

    const int row0 = blockIdx.x * 64;
    const int col0 = blockIdx.y * 64;
    const int tid = threadIdx.x;
    const int tx = tid & 15;
    const int ty = tid >> 4;

    const int arow = tid >> 2;            // 0..63
    const int ak   = (tid & 3) * 4;       // 0..12
    const int brow = tid >> 4;            // 0..15
    const int bcol = (tid & 15) * 4;      // 0..60

    float acc[4][4] = {};

    const int ktiles = K >> 4;
    for (int kt = 0; kt < ktiles; ++kt) {
        const int k0 = kt << 4;
        float4 av = make_float4(0.f, 0.f, 0.f, 0.f);
        const int grow = row0 + arow;
        if (grow < M)
            av = *reinterpret_cast<const float4*>(&A[(size_t)grow * K + k0 + ak]);
        As[ak + 0][arow] = av.x;
        As[ak + 1][arow] = av.y;
        As[ak + 2][arow] = av.z;
        As[ak + 3][arow] = av.w;
        float4 bv = *reinterpret_cast<const float4*>(&B[(size_t)(k0 + brow) * N + col0 + bcol]);
        *reinterpret_cast<float4*>(&Bs[brow][bcol]) = bv;
        __syncthreads();

        #pragma unroll
        for (int kk = 0; kk < 16; ++kk) {
            float4 a4 = *reinterpret_cast<const float4*>(&As[kk][ty * 4]);
            float4 b4 = *reinterpret_cast<const float4*>(&Bs[kk][tx * 4]);
            const float a[4] = {a4.x, a4.y, a4.z, a4.w};
            const float b[4] = {b4.x, b4.y, b4.z, b4.w};
            #pragma unroll
            for (int i = 0; i < 4; ++i)
                #pragma unroll
                for (int j = 0; j < 4; ++j)
                    acc[i][j] = fmaf(a[i], b[j], acc[i][j]);
        }
        __syncthreads();
    }

    float4 bb = make_float4(0.f, 0.f, 0.f, 0.f);
    if (has_bias)
        bb = *reinterpret_cast<const float4*>(&bias[col0 + tx * 4]);
    #pragma unroll
    for (int i = 0; i < 4; ++i) {
        const int r = row0 + ty * 4 + i;
        if (r >= M) continue;
        float4 v = make_float4(acc[i][0] + bb.x, acc[i][1] + bb.y,
                               acc[i][2] + bb.z, acc[i][3] + bb.w);
        *reinterpret_cast<float4*>(&C[(size_t)r * N + col0 + tx * 4]) = v;
    }
}

// ---------------- aggregation ----------------
// hout[i] = dinv[i]*(sum_e dinv[s]*hin[s] + dinv[i]*hin[i]); POST=1: +b1, relu, dropout
template<int POST>
__global__ __launch_bounds__(256) void k_agg(const float* __restrict__ hin,
                                             float* __restrict__ hout,
                                             const int* __restrict__ csr,
                                             const int* __restrict__ rowst,
                                             const int* __restrict__ deg,
                                             const float* __restrict__ dinv,
                                             const float* __restrict__ bias) {
    const int row = blockIdx.x;
    const int ch = threadIdx.x;             // 256 channels
    const float di = dinv[row];
    const int start = rowst[row];
    const int cnt = deg[row] - 1;

    float acc = di * hin[(size_t)row * F_MID + ch];   // self-loop term
    for (int k = 0; k < cnt; ++k) {
        const int s = csr[start + k];
        acc += dinv[s] * hin[(size_t)s * F_MID + ch];
    }
    acc *= di;

    if (POST) {
        acc += bias[ch];
        acc = fmaxf(acc, 0.0f);
        const unsigned f = (unsigned)row * F_MID + (unsigned)ch;
        acc = keep_mask(f) ? acc * 2.0f : 0.0f;
    }
    hout[(size_t)row * F_MID + ch] = acc;
}

// ---------------- launch ----------------
extern "C" void kernel_launch(void* const* d_in, const int* in_sizes, int n_in,
                              void* d_out, int out_size, void* d_ws, size_t ws_size,
                              hipStream_t stream) {
    const float* x  = (const float*)d_in[0];
    const int*   ei = (const int*)d_in[1];
    const float* W1 = (const float*)d_in[2];
    const float* b1 = (const float*)d_in[3];
    const float* W2 = (const float*)d_in[4];
    const float* b2 = (const float*)d_in[5];
    float* out = (float*)d_out;

    // d_out (51.2M floats) doubles as scratch before the final full overwrite:
    float* h0 = out;                            // [N, 256] = x@W1
    float* h1 = out + (size_t)N_NODES * F_MID;  // [N, 256] post relu/dropout

    // workspace layout (~56 MB)
    float* h2agg = (float*)d_ws;                       // [N, 256]
    float* dinv  = h2agg + (size_t)N_NODES * F_MID;    // [N]
    int*   deg   = (int*)(dinv + N_NODES);             // [N]
    int*   rowst = deg + N_NODES;                      // [N]
    int*   cursor= rowst + N_NODES;                    // [N]
    int*   csr   = cursor + N_NODES;                   // [E]
    int*   counter = csr + N_EDGES;                    // [1]
    int*   flag    = counter + 1;                      // [1] 1=int64, 0=int32

    const int nb_n = (N_NODES + 255) / 256;
    const int nb_e = (N_EDGES + 255) / 256;

    k_init  <<<nb_n, 256, 0, stream>>>(deg, cursor, counter, flag);
    k_detect<<<1, 256, 0, stream>>>(ei, flag);
    k_count <<<nb_e, 256, 0, stream>>>(ei, deg, flag);
    k_rows  <<<nb_n, 256, 0, stream>>>(deg, dinv, rowst, counter);
    k_fill  <<<nb_e, 256, 0, stream>>>(ei, rowst, cursor, csr, flag);

    dim3 g1((N_NODES + 63) / 64, F_MID / 64);
    k_gemm<<<g1, 256, 0, stream>>>(x, W1, nullptr, h0, N_NODES, F_MID, F_IN, 0);

    k_agg<1><<<N_NODES, F_MID, 0, stream>>>(h0, h1, csr, rowst, deg, dinv, b1);
    k_agg<0><<<N_NODES, F_MID, 0, stream>>>(h1, h2agg, csr, rowst, deg, dinv, nullptr);

    dim3 g2((N_NODES + 63) / 64, F_IN / 64);
    k_gemm<<<g2, 256, 0, stream>>>(h2agg, W2, b2, out, N_NODES, F_IN, F_MID, 1);
}

// Round 4
// 498.633 us; speedup vs baseline: 2.3017x; 2.3017x over previous
//
#include <hip/hip_runtime.h>
#include <hip/hip_bf16.h>

#define N_NODES 50000
#define N_EDGES 800000
#define F_IN 1024
#define F_MID 256

typedef _Float16 f16;
typedef _Float16 f16x4 __attribute__((ext_vector_type(4)));
typedef _Float16 f16x8 __attribute__((ext_vector_type(8)));
typedef float f32x4 __attribute__((ext_vector_type(4)));

// ---------------- threefry2x32 (JAX-exact, key=(0,42)); verified variant: bits = x0^x1, ctr=(0,f) ----------------
__device__ __forceinline__ void tf_round(unsigned &x0, unsigned &x1, int r) {
    x0 += x1;
    x1 = (x1 << r) | (x1 >> (32 - r));
    x1 ^= x0;
}

__device__ __forceinline__ int keep_mask(unsigned f) {
    const unsigned ks0 = 0u, ks1 = 42u;
    const unsigned ks2 = ks0 ^ ks1 ^ 0x1BD11BDAu;
    unsigned x0 = 0u + ks0;
    unsigned x1 = f + ks1;
    tf_round(x0,x1,13); tf_round(x0,x1,15); tf_round(x0,x1,26); tf_round(x0,x1,6);
    x0 += ks1; x1 += ks2 + 1u;
    tf_round(x0,x1,17); tf_round(x0,x1,29); tf_round(x0,x1,16); tf_round(x0,x1,24);
    x0 += ks2; x1 += ks0 + 2u;
    tf_round(x0,x1,13); tf_round(x0,x1,15); tf_round(x0,x1,26); tf_round(x0,x1,6);
    x0 += ks0; x1 += ks1 + 3u;
    tf_round(x0,x1,17); tf_round(x0,x1,29); tf_round(x0,x1,16); tf_round(x0,x1,24);
    x0 += ks1; x1 += ks2 + 4u;
    tf_round(x0,x1,13); tf_round(x0,x1,15); tf_round(x0,x1,26); tf_round(x0,x1,6);
    x0 += ks2; x1 += ks0 + 5u;
    return (((x0 ^ x1) >> 31) == 0u);   // uniform < 0.5  <=>  MSB clear
}

// ---------------- graph preprocessing ----------------
__global__ __launch_bounds__(256) void k_init(int* deg, int* cursor, int* counter, int* flag) {
    int i = blockIdx.x * 256 + threadIdx.x;
    if (i < N_NODES) { deg[i] = 1; cursor[i] = 0; }   // self-loop
    if (i == 0) { counter[0] = 0; flag[0] = 1; }
}

__global__ __launch_bounds__(256) void k_detect(const int* __restrict__ ei, int* __restrict__ flag) {
    int tid = threadIdx.x;
    int nz = 0;
    for (int k = tid; k < 1024; k += 256) {
        nz |= (ei[2 * k + 1] != 0);
        nz |= (ei[2 * N_EDGES + 2 * k + 1] != 0);
    }
    if (nz) atomicAnd(flag, 0);
}

__device__ __forceinline__ int ld_src(const int* ei, int e, int is64) {
    return is64 ? ei[2 * e] : ei[e];
}
__device__ __forceinline__ int ld_dst(const int* ei, int e, int is64) {
    return is64 ? ei[2 * N_EDGES + 2 * e] : ei[N_EDGES + e];
}

__global__ __launch_bounds__(256) void k_count(const int* __restrict__ ei, int* __restrict__ deg,
                                               const int* __restrict__ flag) {
    int e = blockIdx.x * 256 + threadIdx.x;
    int is64 = flag[0];
    if (e < N_EDGES) atomicAdd(&deg[ld_dst(ei, e, is64)], 1);
}

__global__ __launch_bounds__(256) void k_rows(const int* __restrict__ deg, float* __restrict__ dinv,
                                              int* __restrict__ rowst, int* __restrict__ counter) {
    int i = blockIdx.x * 256 + threadIdx.x;
    if (i < N_NODES) {
        dinv[i] = rsqrtf((float)deg[i]);
        rowst[i] = atomicAdd(counter, deg[i] - 1);
    }
}

__global__ __launch_bounds__(256) void k_fill(const int* __restrict__ ei, const int* __restrict__ rowst,
                                              int* __restrict__ cursor, int* __restrict__ csr,
                                              const int* __restrict__ flag) {
    int e = blockIdx.x * 256 + threadIdx.x;
    int is64 = flag[0];
    if (e < N_EDGES) {
        int d = ld_dst(ei, e, is64);
        int pos = rowst[d] + atomicAdd(&cursor[d], 1);
        csr[pos] = ld_src(ei, e, is64);
    }
}

// ---------------- weight convert+transpose: WT[n][k] = (f16)W[k][n] ----------------
__global__ __launch_bounds__(256) void k_cvtw(const float* __restrict__ W, f16* __restrict__ WT,
                                              int K, int N) {
    int i = blockIdx.x * 256 + threadIdx.x;
    if (i < K * N) {
        int k = i / N, n = i - k * N;
        WT[(size_t)n * K + k] = (f16)W[i];
    }
}

// ---------------- MFMA f16 GEMM ----------------
// C[M,Ntot](tile BMxBN) = A[M,K] @ BT[Ntot,K]^T.
// A16: A is f16 (else f32, converted during stage). C16: C written as f16 row-scaled by dinv;
// else C f32 with +bias. 16x16x32_f16 MFMA; layouts per cdna4 guide (m89-verified C mapping).
template<int BM, int BN, int TN, bool A16, bool C16>
__global__ __launch_bounds__(TN) void k_mfma(const void* __restrict__ Ag,
                                             const f16* __restrict__ BTg,
                                             void* __restrict__ Cg,
                                             const float* __restrict__ bias,
                                             const float* __restrict__ dinv,
                                             int M, int Ntot, int K) {
    constexpr int BK = 64;
    constexpr int LD = 72;               // halves per LDS row (pad 64->72: conflict-free b128 reads)
    __shared__ f16 As[BM * LD];
    __shared__ f16 Bs[BN * LD];

    constexpr int NW = TN / 64;
    constexpr int WM = BM / 64;          // wave-rows
    constexpr int WN = NW / WM;          // wave-cols
    constexpr int WTN = BN / WN;         // wave tile N
    constexpr int FN = WTN / 16;         // n-fragments per wave

    const int tid = threadIdx.x;
    const int lane = tid & 63, wid = tid >> 6;
    const int wm = wid % WM;
    const int wn = wid / WM;
    const int row0 = blockIdx.x * BM;
    const int col0 = blockIdx.y * BN;

    f32x4 acc[4][FN] = {};

    const int nkt = K / BK;
    for (int kt = 0; kt < nkt; ++kt) {
        const int k0 = kt * BK;
        // ---- stage A ----
        if constexpr (A16) {
            const f16* A = (const f16*)Ag;
            constexpr int CH = BM * 8;                    // 16B chunks
            #pragma unroll
            for (int c = tid; c < CH; c += TN) {
                int r = c >> 3, cb = (c & 7) * 8;
                int gr = row0 + r;
                f16x8 v = {};
                if (gr < M) v = *(const f16x8*)&A[(size_t)gr * K + k0 + cb];
                *(f16x8*)&As[r * LD + cb] = v;
            }
        } else {
            const float* A = (const float*)Ag;
            constexpr int CH = BM * 16;                   // 16B f32 chunks (4 floats)
            #pragma unroll
            for (int c = tid; c < CH; c += TN) {
                int r = c >> 4, cb = (c & 15) * 4;
                int gr = row0 + r;
                f32x4 v = {};
                if (gr < M) v = *(const f32x4*)&A[(size_t)gr * K + k0 + cb];
                f16x4 h = __builtin_convertvector(v, f16x4);
                *(f16x4*)&As[r * LD + cb] = h;
            }
        }
        // ---- stage B (BT rows = output cols) ----
        {
            constexpr int CH = BN * 8;
            #pragma unroll
            for (int c = tid; c < CH; c += TN) {
                int r = c >> 3, cb = (c & 7) * 8;
                f16x8 v = *(const f16x8*)&BTg[(size_t)(col0 + r) * K + k0 + cb];
                *(f16x8*)&Bs[r * LD + cb] = v;
            }
        }
        __syncthreads();
        // ---- compute: 2 k-steps of 32 ----
        #pragma unroll
        for (int ks = 0; ks < 2; ++ks) {
            const int kb = ks * 32 + (lane >> 4) * 8;
            f16x8 af[4], bf[FN];
            #pragma unroll
            for (int m = 0; m < 4; ++m)
                af[m] = *(const f16x8*)&As[(wm * 64 + m * 16 + (lane & 15)) * LD + kb];
            #pragma unroll
            for (int n = 0; n < FN; ++n)
                bf[n] = *(const f16x8*)&Bs[(wn * WTN + n * 16 + (lane & 15)) * LD + kb];
            #pragma unroll
            for (int m = 0; m < 4; ++m)
                #pragma unroll
                for (int n = 0; n < FN; ++n)
                    acc[m][n] = __builtin_amdgcn_mfma_f32_16x16x32_f16(af[m], bf[n], acc[m][n], 0, 0, 0);
        }
        __syncthreads();
    }

    // ---- epilogue: C/D mapping col=lane&15, row=(lane>>4)*4+reg ----
    const int rbase = row0 + wm * 64 + (lane >> 4) * 4;
    const int cbase = col0 + wn * WTN + (lane & 15);
    #pragma unroll
    for (int m = 0; m < 4; ++m) {
        #pragma unroll
        for (int j = 0; j < 4; ++j) {
            const int r = rbase + m * 16 + j;
            if (r >= M) continue;
            if constexpr (C16) {
                f16* C = (f16*)Cg;
                const float dv = dinv[r];
                #pragma unroll
                for (int n = 0; n < FN; ++n)
                    C[(size_t)r * Ntot + cbase + n * 16] = (f16)(acc[m][n][j] * dv);
            } else {
                float* C = (float*)Cg;
                #pragma unroll
                for (int n = 0; n < FN; ++n) {
                    const int c = cbase + n * 16;
                    C[(size_t)r * Ntot + c] = acc[m][n][j] + bias[c];
                }
            }
        }
    }
}

// ---------------- aggregation (wave per row, fp16 pre-scaled rows) ----------------
// hin rows are pre-scaled by dinv[src] => acc = hin[row] + sum hin[csr[k]]; out = dinv[row]*acc.
// POST=1: +b1, relu, dropout, then *dinv[row] again (pre-scale for next agg).
template<int POST>
__global__ __launch_bounds__(256) void k_agg16(const f16* __restrict__ hin,
                                               f16* __restrict__ hout,
                                               const int* __restrict__ csr,
                                               const int* __restrict__ rowst,
                                               const int* __restrict__ deg,
                                               const float* __restrict__ dinv,
                                               const float* __restrict__ bias) {
    const int wid = threadIdx.x >> 6;
    const int lane = threadIdx.x & 63;
    const int row = blockIdx.x * 4 + wid;          // grid 12500 * 4 = 50000 exact
    const int start = rowst[row];
    const int cnt = deg[row] - 1;
    const int ch = lane * 4;

    f32x4 acc = __builtin_convertvector(*(const f16x4*)&hin[(size_t)row * F_MID + ch], f32x4);
    for (int k = 0; k < cnt; ++k) {
        const int s = csr[start + k];
        f16x4 v = *(const f16x4*)&hin[(size_t)s * F_MID + ch];
        acc += __builtin_convertvector(v, f32x4);
    }
    const float di = dinv[row];
    acc *= di;

    if (POST) {
        const unsigned f0 = (unsigned)row * F_MID + (unsigned)ch;
        #pragma unroll
        for (int j = 0; j < 4; ++j) {
            float t = acc[j] + bias[ch + j];
            t = fmaxf(t, 0.0f);
            t = keep_mask(f0 + j) ? t * 2.0f : 0.0f;
            acc[j] = t * di;                       // pre-scale for next aggregation
        }
    }
    *(f16x4*)&hout[(size_t)row * F_MID + ch] = __builtin_convertvector(acc, f16x4);
}

// ---------------- launch ----------------
extern "C" void kernel_launch(void* const* d_in, const int* in_sizes, int n_in,
                              void* d_out, int out_size, void* d_ws, size_t ws_size,
                              hipStream_t stream) {
    const float* x  = (const float*)d_in[0];
    const int*   ei = (const int*)d_in[1];
    const float* W1 = (const float*)d_in[2];
    const float* b1 = (const float*)d_in[3];
    const float* W2 = (const float*)d_in[4];
    const float* b2 = (const float*)d_in[5];
    float* out = (float*)d_out;

    // d_out doubles as fp16 scratch (dead before the final f32 overwrite):
    f16* h0s = (f16*)out;                              // [N,256] dinv-scaled xW1
    f16* h1s = h0s + (size_t)N_NODES * F_MID;          // [N,256] dinv-scaled post relu/dropout

    // workspace (~31 MB)
    f16*   h2agg = (f16*)d_ws;                         // [N,256] layer-2 agg out (GEMM2 A)
    f16*   W1T   = h2agg + (size_t)N_NODES * F_MID;    // [256][1024]
    f16*   W2T   = W1T + (size_t)F_MID * F_IN;         // [1024][256]
    float* dinv  = (float*)(W2T + (size_t)F_IN * F_MID);
    int*   deg   = (int*)(dinv + N_NODES);
    int*   rowst = deg + N_NODES;
    int*   cursor= rowst + N_NODES;
    int*   csr   = cursor + N_NODES;
    int*   counter = csr + N_EDGES;
    int*   flag    = counter + 1;

    const int nb_n = (N_NODES + 255) / 256;
    const int nb_e = (N_EDGES + 255) / 256;

    k_init  <<<nb_n, 256, 0, stream>>>(deg, cursor, counter, flag);
    k_detect<<<1, 256, 0, stream>>>(ei, flag);
    k_count <<<nb_e, 256, 0, stream>>>(ei, deg, flag);
    k_rows  <<<nb_n, 256, 0, stream>>>(deg, dinv, rowst, counter);
    k_fill  <<<nb_e, 256, 0, stream>>>(ei, rowst, cursor, csr, flag);

    k_cvtw<<<(F_IN * F_MID + 255) / 256, 256, 0, stream>>>(W1, W1T, F_IN, F_MID);
    k_cvtw<<<(F_MID * F_IN + 255) / 256, 256, 0, stream>>>(W2, W2T, F_MID, F_IN);

    // GEMM1: h0s = dinv .* (x @ W1), fp16 out.  BM=64, BN=256(=N, single col-block)
    {
        dim3 grid((N_NODES + 63) / 64, 1);
        k_mfma<64, 256, 512, false, true><<<grid, 512, 0, stream>>>(
            (const void*)x, W1T, (void*)h0s, nullptr, dinv, N_NODES, F_MID, F_IN);
    }

    k_agg16<1><<<N_NODES / 4, 256, 0, stream>>>(h0s, h1s, csr, rowst, deg, dinv, b1);
    k_agg16<0><<<N_NODES / 4, 256, 0, stream>>>(h1s, h2agg, csr, rowst, deg, dinv, nullptr);

    // GEMM2: out = h2agg @ W2 + b2, f32 out.  BM=128, BN=128, grid 391x8
    {
        dim3 grid((N_NODES + 127) / 128, F_IN / 128);
        k_mfma<128, 128, 256, true, false><<<grid, 256, 0, stream>>>(
            (const void*)h2agg, W2T, (void*)out, b2, dinv, N_NODES, F_IN, F_MID);
    }
}

// Round 5
// 400.587 us; speedup vs baseline: 2.8651x; 1.2448x over previous
//
#include <hip/hip_runtime.h>
#include <hip/hip_bf16.h>

#define N_NODES 50000
#define N_EDGES 800000
#define F_IN 1024
#define F_MID 256

typedef _Float16 f16;
typedef _Float16 f16x4 __attribute__((ext_vector_type(4)));
typedef _Float16 f16x8 __attribute__((ext_vector_type(8)));
typedef float f32x4 __attribute__((ext_vector_type(4)));

// async global->LDS, 16B per lane. lds base must be wave-uniform; global addr per-lane.
__device__ __forceinline__ void glds16(const f16* g, f16* l) {
    __builtin_amdgcn_global_load_lds(
        (const __attribute__((address_space(1))) unsigned int*)g,
        (__attribute__((address_space(3))) unsigned int*)l, 16, 0, 0);
}

// ---------------- threefry2x32 (JAX-exact, key=(0,42)); verified: bits = x0^x1, ctr=(0,f) ----------------
__device__ __forceinline__ void tf_round(unsigned &x0, unsigned &x1, int r) {
    x0 += x1;
    x1 = (x1 << r) | (x1 >> (32 - r));
    x1 ^= x0;
}

__device__ __forceinline__ int keep_mask(unsigned f) {
    const unsigned ks0 = 0u, ks1 = 42u;
    const unsigned ks2 = ks0 ^ ks1 ^ 0x1BD11BDAu;
    unsigned x0 = 0u + ks0;
    unsigned x1 = f + ks1;
    tf_round(x0,x1,13); tf_round(x0,x1,15); tf_round(x0,x1,26); tf_round(x0,x1,6);
    x0 += ks1; x1 += ks2 + 1u;
    tf_round(x0,x1,17); tf_round(x0,x1,29); tf_round(x0,x1,16); tf_round(x0,x1,24);
    x0 += ks2; x1 += ks0 + 2u;
    tf_round(x0,x1,13); tf_round(x0,x1,15); tf_round(x0,x1,26); tf_round(x0,x1,6);
    x0 += ks0; x1 += ks1 + 3u;
    tf_round(x0,x1,17); tf_round(x0,x1,29); tf_round(x0,x1,16); tf_round(x0,x1,24);
    x0 += ks1; x1 += ks2 + 4u;
    tf_round(x0,x1,13); tf_round(x0,x1,15); tf_round(x0,x1,26); tf_round(x0,x1,6);
    x0 += ks2; x1 += ks0 + 5u;
    return (((x0 ^ x1) >> 31) == 0u);
}

// ---------------- graph preprocessing ----------------
__global__ __launch_bounds__(256) void k_init(int* deg, int* cursor, int* counter, int* flag) {
    int i = blockIdx.x * 256 + threadIdx.x;
    if (i < N_NODES) { deg[i] = 1; cursor[i] = 0; }
    if (i == 0) { counter[0] = 0; flag[0] = 1; }
}

__global__ __launch_bounds__(256) void k_detect(const int* __restrict__ ei, int* __restrict__ flag) {
    int tid = threadIdx.x;
    int nz = 0;
    for (int k = tid; k < 1024; k += 256) {
        nz |= (ei[2 * k + 1] != 0);
        nz |= (ei[2 * N_EDGES + 2 * k + 1] != 0);
    }
    if (nz) atomicAnd(flag, 0);
}

__device__ __forceinline__ int ld_src(const int* ei, int e, int is64) {
    return is64 ? ei[2 * e] : ei[e];
}
__device__ __forceinline__ int ld_dst(const int* ei, int e, int is64) {
    return is64 ? ei[2 * N_EDGES + 2 * e] : ei[N_EDGES + e];
}

__global__ __launch_bounds__(256) void k_count(const int* __restrict__ ei, int* __restrict__ deg,
                                               const int* __restrict__ flag) {
    int e = blockIdx.x * 256 + threadIdx.x;
    int is64 = flag[0];
    if (e < N_EDGES) atomicAdd(&deg[ld_dst(ei, e, is64)], 1);
}

__global__ __launch_bounds__(256) void k_rows(const int* __restrict__ deg, float* __restrict__ dinv,
                                              int* __restrict__ rowst, int* __restrict__ counter) {
    int i = blockIdx.x * 256 + threadIdx.x;
    if (i < N_NODES) {
        dinv[i] = rsqrtf((float)deg[i]);
        rowst[i] = atomicAdd(counter, deg[i] - 1);
    }
}

__global__ __launch_bounds__(256) void k_fill(const int* __restrict__ ei, const int* __restrict__ rowst,
                                              int* __restrict__ cursor, int* __restrict__ csr,
                                              const int* __restrict__ flag) {
    int e = blockIdx.x * 256 + threadIdx.x;
    int is64 = flag[0];
    if (e < N_EDGES) {
        int d = ld_dst(ei, e, is64);
        int pos = rowst[d] + atomicAdd(&cursor[d], 1);
        csr[pos] = ld_src(ei, e, is64);
    }
}

// ---------------- weight convert+transpose, PRE-SWIZZLED: WT[n][k ^ ((n&7)<<3)] = (f16)W[k][n] ----------------
__global__ __launch_bounds__(256) void k_cvtw(const float* __restrict__ W, f16* __restrict__ WT,
                                              int K, int N) {
    int i = blockIdx.x * 256 + threadIdx.x;
    if (i < K * N) {
        int k = i / N, n = i - k * N;
        WT[(size_t)n * K + (k ^ ((n & 7) << 3))] = (f16)W[i];
    }
}

// ---------------- MFMA f16 GEMM, double-buffered 2-phase, glds staging, swizzled LDS ----------------
// C[M,Ntot] = A[M,K] @ BT[Ntot,K]^T.  BT pre-swizzled in global.  A16: A is f16 pre-swizzled
// (glds); else f32 (reg-staged + cvt + swizzled ds_write).  C16: f16 out scaled by dinv[row];
// else f32 out + bias.
template<int BM, int BN, int TN, bool A16, bool C16>
__global__ __launch_bounds__(TN) void k_mfma(const void* __restrict__ Ag,
                                             const f16* __restrict__ BTg,
                                             void* __restrict__ Cg,
                                             const float* __restrict__ bias,
                                             const float* __restrict__ dinv,
                                             int M, int Ntot, int K) {
    constexpr int BK = 64;
    constexpr int NW = TN / 64;
    constexpr int WM = BM / 64;
    constexpr int WN = NW / WM;
    constexpr int WTN = BN / WN;
    constexpr int FN = WTN / 16;
    __shared__ f16 As[2][BM * BK];
    __shared__ f16 Bs[2][BN * BK];

    const int tid = threadIdx.x, lane = tid & 63, wid = tid >> 6;
    const int wm = wid % WM, wn = wid / WM;
    const int row0 = blockIdx.x * BM, col0 = blockIdx.y * BN;

    f32x4 acc[4][FN] = {};
    // reg-staging ids (A f32 path; requires TN == BM*8)
    const int ar = tid >> 3;
    const int ac = (tid & 7) * 8;
    f32x4 av0 = {}, av1 = {};

    const int nkt = K / BK;
    int buf = 0;

    auto stage_load = [&](int kt, int b) {
        const int k0 = kt * BK;
        if constexpr (A16) {
            const f16* A = (const f16*)Ag;
            constexpr int nA = BM / 8 / NW;
            #pragma unroll
            for (int j = 0; j < nA; ++j) {
                int i = wid * nA + j;
                int li = i * 512 + lane * 8;
                int r = li >> 6, c = li & 63;
                glds16(&A[(size_t)(row0 + r) * K + k0 + c], &As[b][i * 512]);
            }
        } else {
            const float* A = (const float*)Ag;
            int gr = row0 + ar;
            if (gr < M) {
                av0 = *(const f32x4*)&A[(size_t)gr * K + k0 + ac];
                av1 = *(const f32x4*)&A[(size_t)gr * K + k0 + ac + 4];
            } else { av0 = (f32x4){}; av1 = (f32x4){}; }
        }
        constexpr int nB = BN / 8 / NW;
        #pragma unroll
        for (int j = 0; j < nB; ++j) {
            int i = wid * nB + j;
            int li = i * 512 + lane * 8;
            int r = li >> 6, c = li & 63;
            glds16(&BTg[(size_t)(col0 + r) * K + k0 + c], &Bs[b][i * 512]);
        }
    };
    auto stage_write = [&](int b) {
        if constexpr (!A16) {
            f16x4 l = __builtin_convertvector(av0, f16x4);
            f16x4 h = __builtin_convertvector(av1, f16x4);
            f16x8 v = { l[0], l[1], l[2], l[3], h[0], h[1], h[2], h[3] };
            *(f16x8*)&As[b][ar * 64 + (ac ^ ((ar & 7) << 3))] = v;
        }
    };

    stage_load(0, 0);
    stage_write(0);
    __syncthreads();

    for (int kt = 0; kt < nkt; ++kt) {
        if (kt + 1 < nkt) stage_load(kt + 1, buf ^ 1);
        #pragma unroll
        for (int ks = 0; ks < 2; ++ks) {
            const int cc = ks * 32 + (lane >> 4) * 8;
            f16x8 af[4], bf[FN];
            #pragma unroll
            for (int m = 0; m < 4; ++m) {
                int r = wm * 64 + m * 16 + (lane & 15);
                af[m] = *(const f16x8*)&As[buf][r * 64 + (cc ^ ((r & 7) << 3))];
            }
            #pragma unroll
            for (int n = 0; n < FN; ++n) {
                int r = wn * WTN + n * 16 + (lane & 15);
                bf[n] = *(const f16x8*)&Bs[buf][r * 64 + (cc ^ ((r & 7) << 3))];
            }
            #pragma unroll
            for (int m = 0; m < 4; ++m)
                #pragma unroll
                for (int n = 0; n < FN; ++n)
                    acc[m][n] = __builtin_amdgcn_mfma_f32_16x16x32_f16(af[m], bf[n], acc[m][n], 0, 0, 0);
        }
        if (kt + 1 < nkt) stage_write(buf ^ 1);
        __syncthreads();
        buf ^= 1;
    }

    // ---- epilogue: C/D mapping col=lane&15, row=(lane>>4)*4+reg ----
    const int rbase = row0 + wm * 64 + (lane >> 4) * 4;
    const int cbase = col0 + wn * WTN + (lane & 15);
    #pragma unroll
    for (int m = 0; m < 4; ++m) {
        #pragma unroll
        for (int j = 0; j < 4; ++j) {
            const int r = rbase + m * 16 + j;
            if (r >= M) continue;
            if constexpr (C16) {
                f16* C = (f16*)Cg;
                const float dv = dinv[r];
                #pragma unroll
                for (int n = 0; n < FN; ++n)
                    C[(size_t)r * Ntot + cbase + n * 16] = (f16)(acc[m][n][j] * dv);
            } else {
                float* C = (float*)Cg;
                #pragma unroll
                for (int n = 0; n < FN; ++n) {
                    const int c = cbase + n * 16;
                    C[(size_t)r * Ntot + c] = acc[m][n][j] + bias[c];
                }
            }
        }
    }
}

// ---------------- aggregation (wave per row, pre-scaled fp16 rows, unroll-4 gather) ----------------
// POST=1: +b1, relu, dropout, *dinv (pre-scale for next agg). SWZ: write k-swizzled (GEMM-A layout).
template<int POST, int SWZ>
__global__ __launch_bounds__(256) void k_agg16(const f16* __restrict__ hin,
                                               f16* __restrict__ hout,
                                               const int* __restrict__ csr,
                                               const int* __restrict__ rowst,
                                               const int* __restrict__ deg,
                                               const float* __restrict__ dinv,
                                               const float* __restrict__ bias) {
    const int wid = threadIdx.x >> 6;
    const int lane = threadIdx.x & 63;
    const int row = blockIdx.x * 4 + wid;
    const int start = rowst[row];
    const int cnt = deg[row] - 1;
    const int ch = lane * 4;

    f32x4 acc = __builtin_convertvector(*(const f16x4*)&hin[(size_t)row * F_MID + ch], f32x4);
    int k = 0;
    for (; k + 4 <= cnt; k += 4) {
        const int s0 = csr[start + k], s1 = csr[start + k + 1];
        const int s2 = csr[start + k + 2], s3 = csr[start + k + 3];
        f16x4 v0 = *(const f16x4*)&hin[(size_t)s0 * F_MID + ch];
        f16x4 v1 = *(const f16x4*)&hin[(size_t)s1 * F_MID + ch];
        f16x4 v2 = *(const f16x4*)&hin[(size_t)s2 * F_MID + ch];
        f16x4 v3 = *(const f16x4*)&hin[(size_t)s3 * F_MID + ch];
        acc += __builtin_convertvector(v0, f32x4) + __builtin_convertvector(v1, f32x4)
             + __builtin_convertvector(v2, f32x4) + __builtin_convertvector(v3, f32x4);
    }
    for (; k < cnt; ++k) {
        const int s = csr[start + k];
        acc += __builtin_convertvector(*(const f16x4*)&hin[(size_t)s * F_MID + ch], f32x4);
    }
    const float di = dinv[row];
    acc *= di;

    if (POST) {
        const unsigned f0 = (unsigned)row * F_MID + (unsigned)ch;
        #pragma unroll
        for (int j = 0; j < 4; ++j) {
            float t = acc[j] + bias[ch + j];
            t = fmaxf(t, 0.0f);
            t = keep_mask(f0 + j) ? t * 2.0f : 0.0f;
            acc[j] = t * di;
        }
    }
    const int oc = SWZ ? (ch ^ ((row & 7) << 3)) : ch;
    *(f16x4*)&hout[(size_t)row * F_MID + oc] = __builtin_convertvector(acc, f16x4);
}

// ---------------- launch ----------------
extern "C" void kernel_launch(void* const* d_in, const int* in_sizes, int n_in,
                              void* d_out, int out_size, void* d_ws, size_t ws_size,
                              hipStream_t stream) {
    const float* x  = (const float*)d_in[0];
    const int*   ei = (const int*)d_in[1];
    const float* W1 = (const float*)d_in[2];
    const float* b1 = (const float*)d_in[3];
    const float* W2 = (const float*)d_in[4];
    const float* b2 = (const float*)d_in[5];
    float* out = (float*)d_out;

    // d_out doubles as fp16 scratch (dead before the final f32 overwrite):
    f16* h0s = (f16*)out;                              // [N,256] dinv-scaled xW1 (linear)
    f16* h1s = h0s + (size_t)N_NODES * F_MID;          // [N,256] post relu/dropout (linear)

    // workspace
    f16*   h2agg = (f16*)d_ws;                         // [N,256] agg2 out, k-swizzled (GEMM2 A)
    f16*   W1T   = h2agg + (size_t)N_NODES * F_MID;    // [256][1024] swizzled
    f16*   W2T   = W1T + (size_t)F_MID * F_IN;         // [1024][256] swizzled
    float* dinv  = (float*)(W2T + (size_t)F_IN * F_MID);
    int*   deg   = (int*)(dinv + N_NODES);
    int*   rowst = deg + N_NODES;
    int*   cursor= rowst + N_NODES;
    int*   csr   = cursor + N_NODES;
    int*   counter = csr + N_EDGES;
    int*   flag    = counter + 1;

    const int nb_n = (N_NODES + 255) / 256;
    const int nb_e = (N_EDGES + 255) / 256;

    k_init  <<<nb_n, 256, 0, stream>>>(deg, cursor, counter, flag);
    k_detect<<<1, 256, 0, stream>>>(ei, flag);
    k_count <<<nb_e, 256, 0, stream>>>(ei, deg, flag);
    k_rows  <<<nb_n, 256, 0, stream>>>(deg, dinv, rowst, counter);
    k_fill  <<<nb_e, 256, 0, stream>>>(ei, rowst, cursor, csr, flag);

    k_cvtw<<<(F_IN * F_MID + 255) / 256, 256, 0, stream>>>(W1, W1T, F_IN, F_MID);
    k_cvtw<<<(F_MID * F_IN + 255) / 256, 256, 0, stream>>>(W2, W2T, F_MID, F_IN);

    // GEMM1: h0s = dinv .* (x @ W1).  BM=64, BN=256 (full N), TN=512, grid 782.
    {
        dim3 grid((N_NODES + 63) / 64, 1);
        k_mfma<64, 256, 512, false, true><<<grid, 512, 0, stream>>>(
            (const void*)x, W1T, (void*)h0s, nullptr, dinv, N_NODES, F_MID, F_IN);
    }

    k_agg16<1, 0><<<N_NODES / 4, 256, 0, stream>>>(h0s, h1s, csr, rowst, deg, dinv, b1);
    k_agg16<0, 1><<<N_NODES / 4, 256, 0, stream>>>(h1s, h2agg, csr, rowst, deg, dinv, nullptr);

    // GEMM2: out = h2agg @ W2 + b2.  BM=128, BN=128, TN=512, grid 391x8.
    {
        dim3 grid((N_NODES + 127) / 128, F_IN / 128);
        k_mfma<128, 128, 512, true, false><<<grid, 512, 0, stream>>>(
            (const void*)h2agg, W2T, (void*)out, b2, dinv, N_NODES, F_IN, F_MID);
    }
}

// Round 7
// 349.856 us; speedup vs baseline: 3.2805x; 1.1450x over previous
//
#include <hip/hip_runtime.h>
#include <hip/hip_bf16.h>

#define N_NODES 50000
#define N_EDGES 800000
#define F_IN 1024
#define F_MID 256

typedef _Float16 f16;
typedef _Float16 f16x4 __attribute__((ext_vector_type(4)));
typedef _Float16 f16x8 __attribute__((ext_vector_type(8)));
typedef float f32x4 __attribute__((ext_vector_type(4)));

// async global->LDS, 16B per lane. lds base wave-uniform; global addr per-lane.
__device__ __forceinline__ void glds16(const f16* g, f16* l) {
    __builtin_amdgcn_global_load_lds(
        (const __attribute__((address_space(1))) unsigned int*)g,
        (__attribute__((address_space(3))) unsigned int*)l, 16, 0, 0);
}

// ---------------- threefry2x32 (JAX-exact, key=(0,42)); verified: bits = x0^x1, ctr=(0,f) ----------------
__device__ __forceinline__ void tf_round(unsigned &x0, unsigned &x1, int r) {
    x0 += x1;
    x1 = (x1 << r) | (x1 >> (32 - r));
    x1 ^= x0;
}

__device__ __forceinline__ int keep_mask(unsigned f) {
    const unsigned ks0 = 0u, ks1 = 42u;
    const unsigned ks2 = ks0 ^ ks1 ^ 0x1BD11BDAu;
    unsigned x0 = 0u + ks0;
    unsigned x1 = f + ks1;
    tf_round(x0,x1,13); tf_round(x0,x1,15); tf_round(x0,x1,26); tf_round(x0,x1,6);
    x0 += ks1; x1 += ks2 + 1u;
    tf_round(x0,x1,17); tf_round(x0,x1,29); tf_round(x0,x1,16); tf_round(x0,x1,24);
    x0 += ks2; x1 += ks0 + 2u;
    tf_round(x0,x1,13); tf_round(x0,x1,15); tf_round(x0,x1,26); tf_round(x0,x1,6);
    x0 += ks0; x1 += ks1 + 3u;
    tf_round(x0,x1,17); tf_round(x0,x1,29); tf_round(x0,x1,16); tf_round(x0,x1,24);
    x0 += ks1; x1 += ks2 + 4u;
    tf_round(x0,x1,13); tf_round(x0,x1,15); tf_round(x0,x1,26); tf_round(x0,x1,6);
    x0 += ks2; x1 += ks0 + 5u;
    return (((x0 ^ x1) >> 31) == 0u);
}

__device__ __forceinline__ int ld_src(const int* ei, int e, int is64) {
    return is64 ? ei[2 * e] : ei[e];
}
__device__ __forceinline__ int ld_dst(const int* ei, int e, int is64) {
    return is64 ? ei[2 * N_EDGES + 2 * e] : ei[N_EDGES + e];
}

// ---------------- prep: zero deg/cursor/counter, dtype-detect, cvt+transpose+swizzle W1 ----------------
__global__ __launch_bounds__(256) void k_prep(const float* __restrict__ W1, f16* __restrict__ W1T,
                                              const int* __restrict__ ei,
                                              int* deg, int* cursor, int* counter, int* flag) {
    const int tid = threadIdx.x;
    const int gid = blockIdx.x * 256 + tid;
    const int gstr = gridDim.x * 256;
    if (gid < N_NODES) { deg[gid] = 0; cursor[gid] = 0; }
    if (gid == 0) counter[0] = 0;
    if (blockIdx.x == 0) {
        if (tid == 0) flag[0] = 1;            // 1 = int64
        __syncthreads();
        // int64 hypothesis: hi words of src values (<50000) are all zero.
        int nz = 0;
        for (int k = tid; k < 1024; k += 256) nz |= (ei[2 * k + 1] != 0);
        if (nz) atomicAnd(flag, 0);
    }
    for (int i = gid; i < F_IN * F_MID; i += gstr) {
        int k = i >> 8, n = i & 255;          // W1 [1024][256]
        W1T[(size_t)n * F_IN + (k ^ ((n & 7) << 3))] = (f16)W1[i];
    }
}

__global__ __launch_bounds__(256) void k_rows(const int* __restrict__ deg, float* __restrict__ dinv,
                                              int* __restrict__ rowst, int* __restrict__ counter) {
    int i = blockIdx.x * 256 + threadIdx.x;
    if (i < N_NODES) {
        dinv[i] = rsqrtf((float)(deg[i] + 1));       // +1 self-loop
        rowst[i] = atomicAdd(counter, deg[i]);
    }
}

__global__ __launch_bounds__(256) void k_fill(const int* __restrict__ ei, const int* __restrict__ rowst,
                                              int* __restrict__ cursor, int* __restrict__ csr,
                                              const int* __restrict__ flag) {
    int e = blockIdx.x * 256 + threadIdx.x;
    int is64 = flag[0];
    if (e < N_EDGES) {
        int d = ld_dst(ei, e, is64);
        int pos = rowst[d] + atomicAdd(&cursor[d], 1);
        csr[pos] = ld_src(ei, e, is64);
    }
}

// ---------------- MFMA f16 GEMM, double-buffered 2-phase, glds staging, swizzled LDS ----------------
// C[M,Ntot] = A[M,K] @ BT[Ntot,K]^T.  BT pre-swizzled.  A16: A f16 pre-swizzled (glds);
// else f32 reg-staged + cvt + swizzled ds_write.  C16: f16 out (UNSCALED); else f32 + bias.
// Blocks with blockIdx.x >= mainx are RIDERS: edge-degree count + cvt/transpose W2 (overlap).
template<int BM, int BN, int TN, bool A16, bool C16>
__global__ __launch_bounds__(TN) void k_mfma(const void* __restrict__ Ag,
                                             const f16* __restrict__ BTg,
                                             void* __restrict__ Cg,
                                             const float* __restrict__ bias,
                                             int M, int Ntot, int K, int mainx,
                                             const int* __restrict__ ei, int* __restrict__ deg,
                                             const int* __restrict__ flag,
                                             const float* __restrict__ Wr, f16* __restrict__ WrT) {
    if ((int)blockIdx.x >= mainx) {
        const int str = (gridDim.x - mainx) * TN;
        const int t0 = (blockIdx.x - mainx) * TN + threadIdx.x;
        const int is64 = flag[0];
        for (int e = t0; e < N_EDGES; e += str)
            atomicAdd(&deg[ld_dst(ei, e, is64)], 1);
        for (int i = t0; i < F_MID * F_IN; i += str) {
            int k = i >> 10, n = i & 1023;    // Wr [256][1024]
            WrT[(size_t)n * F_MID + (k ^ ((n & 7) << 3))] = (f16)Wr[i];
        }
        return;
    }

    constexpr int BK = 64;
    constexpr int NW = TN / 64;
    constexpr int WM = BM / 64;
    constexpr int WN = NW / WM;
    constexpr int WTN = BN / WN;
    constexpr int FN = WTN / 16;
    __shared__ f16 As[2][BM * BK];
    __shared__ f16 Bs[2][BN * BK];

    const int tid = threadIdx.x, lane = tid & 63, wid = tid >> 6;
    const int wm = wid % WM, wn = wid / WM;
    const int row0 = blockIdx.x * BM, col0 = blockIdx.y * BN;

    f32x4 acc[4][FN] = {};
    const int ar = tid >> 3;              // f32 A reg-staging (TN == BM*8)
    const int ac = (tid & 7) * 8;
    f32x4 av0 = {}, av1 = {};

    const int nkt = K / BK;
    int buf = 0;

    auto stage_load = [&](int kt, int b) {
        const int k0 = kt * BK;
        if constexpr (A16) {
            const f16* A = (const f16*)Ag;
            constexpr int nA = BM / 8 / NW;
            #pragma unroll
            for (int j = 0; j < nA; ++j) {
                int i = wid * nA + j;
                int li = i * 512 + lane * 8;
                int r = li >> 6, c = li & 63;
                glds16(&A[(size_t)(row0 + r) * K + k0 + c], &As[b][i * 512]);
            }
        } else {
            const float* A = (const float*)Ag;
            int gr = row0 + ar;
            if (gr < M) {
                av0 = *(const f32x4*)&A[(size_t)gr * K + k0 + ac];
                av1 = *(const f32x4*)&A[(size_t)gr * K + k0 + ac + 4];
            } else { av0 = (f32x4){}; av1 = (f32x4){}; }
        }
        constexpr int nB = BN / 8 / NW;
        #pragma unroll
        for (int j = 0; j < nB; ++j) {
            int i = wid * nB + j;
            int li = i * 512 + lane * 8;
            int r = li >> 6, c = li & 63;
            glds16(&BTg[(size_t)(col0 + r) * K + k0 + c], &Bs[b][i * 512]);
        }
    };
    auto stage_write = [&](int b) {
        if constexpr (!A16) {
            f16x4 l = __builtin_convertvector(av0, f16x4);
            f16x4 h = __builtin_convertvector(av1, f16x4);
            f16x8 v = { l[0], l[1], l[2], l[3], h[0], h[1], h[2], h[3] };
            *(f16x8*)&As[b][ar * 64 + (ac ^ ((ar & 7) << 3))] = v;
        }
    };

    stage_load(0, 0);
    stage_write(0);
    __syncthreads();

    for (int kt = 0; kt < nkt; ++kt) {
        if (kt + 1 < nkt) stage_load(kt + 1, buf ^ 1);
        #pragma unroll
        for (int ks = 0; ks < 2; ++ks) {
            const int cc = ks * 32 + (lane >> 4) * 8;
            f16x8 af[4], bf[FN];
            #pragma unroll
            for (int m = 0; m < 4; ++m) {
                int r = wm * 64 + m * 16 + (lane & 15);
                af[m] = *(const f16x8*)&As[buf][r * 64 + (cc ^ ((r & 7) << 3))];
            }
            #pragma unroll
            for (int n = 0; n < FN; ++n) {
                int r = wn * WTN + n * 16 + (lane & 15);
                bf[n] = *(const f16x8*)&Bs[buf][r * 64 + (cc ^ ((r & 7) << 3))];
            }
            #pragma unroll
            for (int m = 0; m < 4; ++m)
                #pragma unroll
                for (int n = 0; n < FN; ++n)
                    acc[m][n] = __builtin_amdgcn_mfma_f32_16x16x32_f16(af[m], bf[n], acc[m][n], 0, 0, 0);
        }
        if (kt + 1 < nkt) stage_write(buf ^ 1);
        __syncthreads();
        buf ^= 1;
    }

    // epilogue: C/D mapping col=lane&15, row=(lane>>4)*4+reg
    const int rbase = row0 + wm * 64 + (lane >> 4) * 4;
    const int cbase = col0 + wn * WTN + (lane & 15);
    #pragma unroll
    for (int m = 0; m < 4; ++m) {
        #pragma unroll
        for (int j = 0; j < 4; ++j) {
            const int r = rbase + m * 16 + j;
            if (r >= M) continue;
            if constexpr (C16) {
                f16* C = (f16*)Cg;
                #pragma unroll
                for (int n = 0; n < FN; ++n)
                    C[(size_t)r * Ntot + cbase + n * 16] = (f16)acc[m][n][j];
            } else {
                float* C = (float*)Cg;
                #pragma unroll
                for (int n = 0; n < FN; ++n) {
                    const int c = cbase + n * 16;
                    C[(size_t)r * Ntot + c] = acc[m][n][j] + bias[c];
                }
            }
        }
    }
}

// ---------------- aggregation (wave per row, unroll-4 gather) ----------------
// SCALED_IN=1: input rows already carry dinv[src]  -> acc = hin[row] + sum hin[s]
// SCALED_IN=0: input unscaled                      -> acc = dinv[row]*hin[row] + sum dinv[s]*hin[s]
// Then acc *= dinv[row].  POST=1: +b1, relu, dropout, *dinv[row] (pre-scale for next agg).
// SWZ=1: write k-swizzled (GEMM2-A glds layout).
template<int POST, int SWZ, int SCALED_IN>
__global__ __launch_bounds__(256) void k_agg16(const f16* __restrict__ hin,
                                               f16* __restrict__ hout,
                                               const int* __restrict__ csr,
                                               const int* __restrict__ rowst,
                                               const int* __restrict__ deg,
                                               const float* __restrict__ dinv,
                                               const float* __restrict__ bias) {
    const int wid = threadIdx.x >> 6;
    const int lane = threadIdx.x & 63;
    const int row = blockIdx.x * 4 + wid;
    const int start = rowst[row];
    const int cnt = deg[row];
    const int ch = lane * 4;
    const float di = dinv[row];

    f32x4 acc = __builtin_convertvector(*(const f16x4*)&hin[(size_t)row * F_MID + ch], f32x4);
    if (!SCALED_IN) acc *= di;
    int k = 0;
    for (; k + 4 <= cnt; k += 4) {
        const int s0 = csr[start + k], s1 = csr[start + k + 1];
        const int s2 = csr[start + k + 2], s3 = csr[start + k + 3];
        f16x4 v0 = *(const f16x4*)&hin[(size_t)s0 * F_MID + ch];
        f16x4 v1 = *(const f16x4*)&hin[(size_t)s1 * F_MID + ch];
        f16x4 v2 = *(const f16x4*)&hin[(size_t)s2 * F_MID + ch];
        f16x4 v3 = *(const f16x4*)&hin[(size_t)s3 * F_MID + ch];
        if (SCALED_IN) {
            acc += __builtin_convertvector(v0, f32x4) + __builtin_convertvector(v1, f32x4)
                 + __builtin_convertvector(v2, f32x4) + __builtin_convertvector(v3, f32x4);
        } else {
            acc += dinv[s0] * __builtin_convertvector(v0, f32x4)
                 + dinv[s1] * __builtin_convertvector(v1, f32x4)
                 + dinv[s2] * __builtin_convertvector(v2, f32x4)
                 + dinv[s3] * __builtin_convertvector(v3, f32x4);
        }
    }
    for (; k < cnt; ++k) {
        const int s = csr[start + k];
        f32x4 v = __builtin_convertvector(*(const f16x4*)&hin[(size_t)s * F_MID + ch], f32x4);
        acc += SCALED_IN ? v : dinv[s] * v;
    }
    acc *= di;

    if (POST) {
        const unsigned f0 = (unsigned)row * F_MID + (unsigned)ch;
        #pragma unroll
        for (int j = 0; j < 4; ++j) {
            float t = acc[j] + bias[ch + j];
            t = fmaxf(t, 0.0f);
            t = keep_mask(f0 + j) ? t * 2.0f : 0.0f;
            acc[j] = t * di;                 // pre-scale for next aggregation
        }
    }
    const int oc = SWZ ? (ch ^ ((row & 7) << 3)) : ch;
    *(f16x4*)&hout[(size_t)row * F_MID + oc] = __builtin_convertvector(acc, f16x4);
}

// ---------------- launch ----------------
extern "C" void kernel_launch(void* const* d_in, const int* in_sizes, int n_in,
                              void* d_out, int out_size, void* d_ws, size_t ws_size,
                              hipStream_t stream) {
    const float* x  = (const float*)d_in[0];
    const int*   ei = (const int*)d_in[1];
    const float* W1 = (const float*)d_in[2];
    const float* b1 = (const float*)d_in[3];
    const float* W2 = (const float*)d_in[4];
    const float* b2 = (const float*)d_in[5];
    float* out = (float*)d_out;

    // d_out doubles as fp16 scratch (dead before the final f32 overwrite):
    f16* h0 = (f16*)out;                               // [N,256] xW1, UNSCALED (linear)
    f16* h1s = h0 + (size_t)N_NODES * F_MID;           // [N,256] post relu/dropout, dinv-scaled (linear)

    // workspace
    f16*   h2agg = (f16*)d_ws;                         // [N,256] agg2 out, k-swizzled (GEMM2 A)
    f16*   W1T   = h2agg + (size_t)(N_NODES + 64) * F_MID;  // [256][1024] swizzled (+pad: OOB-safe glds)
    f16*   W2T   = W1T + (size_t)F_MID * F_IN;         // [1024][256] swizzled
    float* dinv  = (float*)(W2T + (size_t)F_IN * F_MID);
    int*   deg   = (int*)(dinv + N_NODES);
    int*   rowst = deg + N_NODES;
    int*   cursor= rowst + N_NODES;
    int*   csr   = cursor + N_NODES;
    int*   counter = csr + N_EDGES;
    int*   flag    = counter + 1;

    // 1) prep: zero counters, dtype detect, W1 -> W1T (swizzled)
    k_prep<<<256, 256, 0, stream>>>(W1, W1T, ei, deg, cursor, counter, flag);

    // 2) GEMM1 (+riders: edge-degree count, W2 -> W2T): h0 = x @ W1  (unscaled: no dinv dependency)
    {
        const int mainx = (N_NODES + 63) / 64;         // 782
        dim3 grid(mainx + 384, 1);
        k_mfma<64, 256, 512, false, true><<<grid, 512, 0, stream>>>(
            (const void*)x, W1T, (void*)h0, nullptr, N_NODES, F_MID, F_IN,
            mainx, ei, deg, flag, W2, W2T);
    }

    // 3) rows (dinv, rowst), 4) fill (csr)
    k_rows<<<(N_NODES + 255) / 256, 256, 0, stream>>>(deg, dinv, rowst, counter);
    k_fill<<<(N_EDGES + 255) / 256, 256, 0, stream>>>(ei, rowst, cursor, csr, flag);

    // 5) agg1: unscaled input -> dinv[s]-weighted gather; +b1, relu, dropout, pre-scale
    k_agg16<1, 0, 0><<<N_NODES / 4, 256, 0, stream>>>(h0, h1s, csr, rowst, deg, dinv, b1);
    // 6) agg2: pre-scaled input; swizzled out (GEMM2 A layout)
    k_agg16<0, 1, 1><<<N_NODES / 4, 256, 0, stream>>>(h1s, h2agg, csr, rowst, deg, dinv, nullptr);

    // 7) GEMM2: out = h2agg @ W2 + b2.  BM=64, BN=256, grid (782,4) — A read 4x.
    {
        const int mainx = (N_NODES + 63) / 64;
        dim3 grid(mainx, 4);
        k_mfma<64, 256, 512, true, false><<<grid, 512, 0, stream>>>(
            (const void*)h2agg, W2T, (void*)out, b2, N_NODES, F_IN, F_MID,
            mainx, ei, deg, flag, W2, W2T);
    }
}